// Round 18
// baseline (201.572 us; speedup 1.0000x reference)
//
#include <hip/hip_runtime.h>
#include <hip/hip_bf16.h>

// B=32, C=64, H=W=112. Per-sample 3x3 convs via bf16 MFMA implicit GEMM.
// conv1 stages B directly from x (f32 NCHW gather + cvt_pk + zero-pad mask);
// conv2 reads y1 half-planes [b][half(ci32)][slot][32ci], slot = POFF+y*113+x
// (col 112 = zero border, masked during staging).
// Conv block (448 thr = 7 waves): W staged via global_load_lds (73.7KB), one
// ci-half B window (1024 slots) in LDS; k-loop = pure {ds_read A, ds_read B,
// MFMA}. Wave = 64co x 112px (7 frags, acc[7][4]).
// r18: (1) bt slot stride padded 64B->80B: B-read bank pattern (px*20+kg*4)%32
// = 2-way = free (was 8-way, 1.8M conflicts); (2) all hot f32->bf16 paths use
// __float22bfloat162_rn (v_cvt_pk_bf16_f32) instead of 5-op bit-twiddle.
#define HW   112
#define HW2  12544
#define CH   64
#define NB   32
#define PRW  113
#define NP   12655          // interior slots per sample
#define POFF 128
#define PS   13056          // slots per half-plane per sample
#define NPC  (NB*HW2)
#define TPX  784            // pixels per conv tile (= 7 rows)
#define BTS  40             // bt slot stride in u16 (80 B, bank-padded)

using u16 = unsigned short;
typedef __attribute__((ext_vector_type(8))) short bf16x8;   // 8 bf16 = 4 VGPRs
typedef __attribute__((ext_vector_type(4))) float f32x4;

__device__ __forceinline__ float b2f(u16 u) {
    union { unsigned int i; float f; } c;
    c.i = ((unsigned int)u) << 16;
    return c.f;
}
__device__ __forceinline__ u16 f2b(float f) {               // repack only (cold)
    union { float f; unsigned int i; } c;
    c.f = f;
    unsigned int x = c.i;
    x += 0x7fffu + ((x >> 16) & 1u);   // RNE
    return (u16)(x >> 16);
}
// pair f32 -> packed bf16x2 (RNE) via v_cvt_pk_bf16_f32; a = low, b = high
__device__ __forceinline__ unsigned pk2(float a, float b) {
    __hip_bfloat162 h = __float22bfloat162_rn(float2{a, b});
    union { __hip_bfloat162 h; unsigned u; } c; c.h = h; return c.u;
}

// async global->LDS, 16B per lane; l must be the WAVE-UNIFORM base
// (HW dest = base + lane*16). Drained by __syncthreads' vmcnt(0).
__device__ __forceinline__ void gl2lds(const u16* g, u16* l) {
    __builtin_amdgcn_global_load_lds(
        (const __attribute__((address_space(1))) unsigned int*)g,
        (__attribute__((address_space(3))) unsigned int*)l, 16, 0, 0);
}

// MODE 0: conv1 (input = x f32 NCHW, transpose+pad+convert fused into staging;
//                output = y1 half-planes, interior slots only)
// MODE 1: conv2 (input = y1 half-planes with BN1 affine+ReLU applied during
//                staging, pad slots masked to 0; output = COMPACT y2 [b][pix][64])
// wt: bf16 [b][half][tap][kq][co][8ci] (73728 B / sample, matches LDS layout).
template<int MODE>
__global__ __launch_bounds__(448, 2)
void conv_mfma(const float* __restrict__ xf, const u16* __restrict__ img,
               const u16* __restrict__ wt,
               u16* __restrict__ outp, float* __restrict__ sums,
               const float* __restrict__ psums, const float* __restrict__ gamma,
               const float* __restrict__ beta)
{
    __shared__ u16 wl[36864];            // 73728 B weights, both halves
    __shared__ u16 bt[1024 * BTS];       // 81920 B: 1024 slots x 32ci, 80B stride
    // XCD swizzle: 512 = 8 x 64 -> each XCD gets 4 whole samples.
    const int bid = (int)blockIdx.x;
    const int sid = (bid & 7) * 64 + (bid >> 3);
    const int b = sid >> 4, tile = sid & 15;
    const int p0 = tile * TPX;           // first pixel of tile
    const int w0 = tile * 791 - 114;     // staged window start (slot space)
    const int tid = threadIdx.x;
    const int lane = tid & 63, wave = tid >> 6;   // wave 0..6
    const int px = lane & 15, kg = lane >> 4;
    const u16* wtb = wt + (size_t)b * 36864;

    // ---- stage ALL weights: async gllds, waves 0-5, 12 chunks each ----
    if (tid < 384) {
#pragma unroll
        for (int i = 0; i < 12; ++i) {
            const int c = i * 384 + tid;                 // 4608 chunks exact
            gl2lds(wtb + (size_t)c * 8, wl + (size_t)(c - lane) * 8);
        }
    }

    // ---- BN1 params for MODE1 staging (q = tid&3 loop-invariant: 448%4==0) ----
    float sc0[8], bi0[8], sc1[8], bi1[8];
    if (MODE == 1) {
        const int q = tid & 3;
#pragma unroll
        for (int e = 0; e < 8; ++e) {
            int c0 = q * 8 + e, c1 = 32 + q * 8 + e;
            float m0 = psums[c0] * (1.f / NPC), m1 = psums[c1] * (1.f / NPC);
            float v0 = psums[64 + c0] * (1.f / NPC) - m0 * m0;
            float v1 = psums[64 + c1] * (1.f / NPC) - m1 * m1;
            sc0[e] = gamma[c0] * rsqrtf(v0 + 1e-5f); bi0[e] = beta[c0] - m0 * sc0[e];
            sc1[e] = gamma[c1] * rsqrtf(v1 + 1e-5f); bi1[e] = beta[c1] - m1 * sc1[e];
        }
    }
    const float* xb = (MODE == 0) ? xf + (size_t)b * CH * HW2 : nullptr;

    // ---- stage B half 0 ----
    {
        const u16* bp = img + ((size_t)(b * 2 + 0) * PS + POFF + w0) * 32;
        for (int c = tid; c < 4096; c += 448) {
            const int pt = w0 + (c >> 2);
            uint4 u = {0u, 0u, 0u, 0u};
            if (MODE == 0) {
                if ((unsigned)pt < (unsigned)NP) {
                    int y  = (unsigned)pt / PRW;
                    int xc = pt - y * PRW;
                    if (xc != PRW - 1) {
                        const float* src = xb + (size_t)((c & 3) * 8) * HW2 + y * HW + xc;
                        float f0 = src[0], f1 = src[(size_t)1 * HW2];
                        float f2 = src[(size_t)2 * HW2], f3 = src[(size_t)3 * HW2];
                        float f4 = src[(size_t)4 * HW2], f5 = src[(size_t)5 * HW2];
                        float f6 = src[(size_t)6 * HW2], f7 = src[(size_t)7 * HW2];
                        u.x = pk2(f0, f1); u.y = pk2(f2, f3);
                        u.z = pk2(f4, f5); u.w = pk2(f6, f7);
                    }
                }
            } else {
                bool val = ((unsigned)pt < (unsigned)NP) && (pt % PRW != PRW - 1);
                bf16x8 r = *(const bf16x8*)(bp + c * 8);
                float t[8];
#pragma unroll
                for (int e = 0; e < 8; ++e) {
                    float v = b2f((u16)r[e]) * sc0[e] + bi0[e];
                    t[e] = (val && v > 0.f) ? v : 0.f;
                }
                u.x = pk2(t[0], t[1]); u.y = pk2(t[2], t[3]);
                u.z = pk2(t[4], t[5]); u.w = pk2(t[6], t[7]);
            }
            *(uint4*)(bt + (c >> 2) * BTS + (c & 3) * 8) = u;
        }
    }
    __syncthreads();

    // ---- per-fragment LDS slot bases (pixel -> slot, pre-scaled by BTS) ----
    int lsfb[7];
#pragma unroll
    for (int f = 0; f < 7; ++f) {
        const int pix = p0 + (wave * 7 + f) * 16 + px;
        lsfb[f] = (pix + pix / HW - w0) * BTS;
    }

    f32x4 acc[7][4];
#pragma unroll
    for (int f = 0; f < 7; ++f)
#pragma unroll
        for (int m = 0; m < 4; ++m) acc[f][m] = (f32x4)0.f;

    // ---- main loop: 2 ci-halves x 9 taps; pure LDS + MFMA ----
#pragma unroll
    for (int h = 0; h < 2; ++h) {
        if (h == 1) {
            __syncthreads();             // all waves done with half-0 B tile
            const u16* bp = img + ((size_t)(b * 2 + 1) * PS + POFF + w0) * 32;
            for (int c = tid; c < 4096; c += 448) {
                const int pt = w0 + (c >> 2);
                uint4 u = {0u, 0u, 0u, 0u};
                if (MODE == 0) {
                    if ((unsigned)pt < (unsigned)NP) {
                        int y  = (unsigned)pt / PRW;
                        int xc = pt - y * PRW;
                        if (xc != PRW - 1) {
                            const float* src = xb + (size_t)(32 + (c & 3) * 8) * HW2 + y * HW + xc;
                            float f0 = src[0], f1 = src[(size_t)1 * HW2];
                            float f2 = src[(size_t)2 * HW2], f3 = src[(size_t)3 * HW2];
                            float f4 = src[(size_t)4 * HW2], f5 = src[(size_t)5 * HW2];
                            float f6 = src[(size_t)6 * HW2], f7 = src[(size_t)7 * HW2];
                            u.x = pk2(f0, f1); u.y = pk2(f2, f3);
                            u.z = pk2(f4, f5); u.w = pk2(f6, f7);
                        }
                    }
                } else {
                    bool val = ((unsigned)pt < (unsigned)NP) && (pt % PRW != PRW - 1);
                    bf16x8 r = *(const bf16x8*)(bp + c * 8);
                    float t[8];
#pragma unroll
                    for (int e = 0; e < 8; ++e) {
                        float v = b2f((u16)r[e]) * sc1[e] + bi1[e];
                        t[e] = (val && v > 0.f) ? v : 0.f;
                    }
                    u.x = pk2(t[0], t[1]); u.y = pk2(t[2], t[3]);
                    u.z = pk2(t[4], t[5]); u.w = pk2(t[6], t[7]);
                }
                *(uint4*)(bt + (c >> 2) * BTS + (c & 3) * 8) = u;
            }
            __syncthreads();
        }
#pragma unroll
        for (int tap = 0; tap < 9; ++tap) {
            const int off = ((tap / 3 - 1) * PRW + (tap % 3 - 1)) * BTS;
            bf16x8 Af[4];
#pragma unroll
            for (int m = 0; m < 4; ++m)
                Af[m] = *(const bf16x8*)(wl + h * 18432 + tap * 2048 + kg * 512 + (m * 16 + px) * 8);
#pragma unroll
            for (int f = 0; f < 7; ++f) {
                bf16x8 Bf = *(const bf16x8*)(bt + lsfb[f] + off + kg * 8);
#pragma unroll
                for (int m = 0; m < 4; ++m)
                    acc[f][m] = __builtin_amdgcn_mfma_f32_16x16x32_bf16(Af[m], Bf, acc[f][m], 0, 0, 0);
            }
        }
    }

    // ---- epilogue: unpredicated stores + fused BN batch-stat partials ----
    float s_[4][4], sq[4][4];
#pragma unroll
    for (int m = 0; m < 4; ++m)
#pragma unroll
        for (int q = 0; q < 4; ++q) { s_[m][q] = 0.f; sq[m][q] = 0.f; }

#pragma unroll
    for (int f = 0; f < 7; ++f) {
        const int pix  = p0 + (wave * 7 + f) * 16 + px;
        const int slot = pix + pix / HW;
#pragma unroll
        for (int m = 0; m < 4; ++m) {
            float v0 = acc[f][m][0], v1 = acc[f][m][1], v2 = acc[f][m][2], v3 = acc[f][m][3];
            s_[m][0] += v0; s_[m][1] += v1; s_[m][2] += v2; s_[m][3] += v3;
            sq[m][0] += v0 * v0; sq[m][1] += v1 * v1;
            sq[m][2] += v2 * v2; sq[m][3] += v3 * v3;
            uint2 pk;
            pk.x = pk2(v0, v1);
            pk.y = pk2(v2, v3);
            if (MODE == 0) {
                // y1 half-planes: half = m>>1, within-half co = (m&1)*16+kg*4
                u16* dst = outp + ((size_t)(b * 2 + (m >> 1)) * PS + POFF + slot) * 32
                                + (m & 1) * 16 + kg * 4;
                *(uint2*)dst = pk;
            } else {
                // compact y2 [b][pix][64]
                u16* dst = outp + ((size_t)b * HW2 + pix) * 64 + m * 16 + kg * 4;
                *(uint2*)dst = pk;
            }
        }
    }
#pragma unroll
    for (int off = 1; off < 16; off <<= 1) {
#pragma unroll
        for (int m = 0; m < 4; ++m)
#pragma unroll
            for (int q = 0; q < 4; ++q) {
                s_[m][q] += __shfl_xor(s_[m][q], off);
                sq[m][q] += __shfl_xor(sq[m][q], off);
            }
    }
    __syncthreads();                     // bt reads done; reuse as reduce buffer
    float* red = (float*)bt;             // 7 waves x 128 floats
    if (px == 0) {
#pragma unroll
        for (int m = 0; m < 4; ++m)
#pragma unroll
            for (int q = 0; q < 4; ++q) {
                int c = m * 16 + kg * 4 + q;
                red[wave * 128 + c]      = s_[m][q];
                red[wave * 128 + 64 + c] = sq[m][q];
            }
    }
    __syncthreads();
    if (tid < 128) {
        float t = 0.f;
#pragma unroll
        for (int k = 0; k < 7; ++k) t += red[k * 128 + tid];
        atomicAdd(&sums[tid], t);
    }
}

// both weights: [b][co][ci][3][3] f32 -> [b][half][tap][kq][co][8ci] bf16.
// Extra trailing block zeroes the stats area.
__global__ __launch_bounds__(256)
void repack2_kernel(const float* __restrict__ w1, const float* __restrict__ w2,
                    u16* __restrict__ wt1, u16* __restrict__ wt2,
                    float* __restrict__ st)
{
    if (blockIdx.x == 9216) {
        st[threadIdx.x] = 0.f;           // 256 floats (sums1 + sums2)
        return;
    }
    int i = blockIdx.x * 256 + threadIdx.x;      // 0..2359295
    const int N = NB * 36864;
    const float* w = (i < N) ? w1 : w2;
    u16* wt = (i < N) ? wt1 : wt2;
    int o = (i < N) ? i : i - N;
    int b = o / 36864, r = o - b * 36864;
    int half = r / 18432; r -= half * 18432;
    int tap  = r / 2048;  r -= tap * 2048;
    int kq   = r / 512;   r -= kq * 512;
    int co   = r / 8;
    int ci   = half * 32 + kq * 8 + (r & 7);
    wt[o] = f2b(w[(((size_t)b * 64 + co) * 64 + ci) * 9 + tap]);
}

// out = relu(bn2(y2) + x), NCHW f32 via LDS transpose; y2 compact [b][pix][64]
__global__ __launch_bounds__(256)
void finalize_kernel(const u16* __restrict__ y2, const float* __restrict__ sums,
                     const float* __restrict__ gamma, const float* __restrict__ beta,
                     const float* __restrict__ x, float* __restrict__ out)
{
    __shared__ float lt[64][116];
    __shared__ float sbl[128];
    const int b = blockIdx.y, y = blockIdx.x;
    const int tid = threadIdx.x;
    if (tid < 64) {
        float mean = sums[tid] * (1.f / NPC);
        float var  = sums[64 + tid] * (1.f / NPC) - mean * mean;
        float sc   = gamma[tid] * rsqrtf(var + 1e-5f);
        sbl[tid]      = sc;
        sbl[64 + tid] = beta[tid] - mean * sc;
    }
    __syncthreads();
    const u16* rowp = y2 + ((size_t)b * HW2 + (size_t)y * HW) * 64;
    {
        const int cg = tid & 7;
        float sc[8], bi[8];
#pragma unroll
        for (int e = 0; e < 8; ++e) { sc[e] = sbl[cg * 8 + e]; bi[e] = sbl[64 + cg * 8 + e]; }
        for (int t = tid; t < HW * 8; t += 256) {
            int px = t >> 3;
            bf16x8 v = *(const bf16x8*)(rowp + px * 64 + cg * 8);
#pragma unroll
            for (int e = 0; e < 8; ++e)
                lt[cg * 8 + e][px] = b2f((u16)v[e]) * sc[e] + bi[e];
        }
    }
    __syncthreads();
    {
        const int c = tid >> 2, xg = (tid & 3) * 28;
        size_t base = ((size_t)b * CH + c) * HW2 + (size_t)y * HW + xg;
#pragma unroll
        for (int i = 0; i < 7; ++i) {
            float4 xv = *(const float4*)(x + base + i * 4);
            float4 r;
            r.x = fmaxf(lt[c][xg + i * 4 + 0] + xv.x, 0.f);
            r.y = fmaxf(lt[c][xg + i * 4 + 1] + xv.y, 0.f);
            r.z = fmaxf(lt[c][xg + i * 4 + 2] + xv.z, 0.f);
            r.w = fmaxf(lt[c][xg + i * 4 + 3] + xv.w, 0.f);
            *(float4*)(out + base + i * 4) = r;
        }
    }
}

extern "C" void kernel_launch(void* const* d_in, const int* in_sizes, int n_in,
                              void* d_out, int out_size, void* d_ws, size_t ws_size,
                              hipStream_t stream)
{
    const float* x  = (const float*)d_in[0];
    const float* w1 = (const float*)d_in[1];
    const float* w2 = (const float*)d_in[2];
    const float* g1 = (const float*)d_in[3];
    const float* b1 = (const float*)d_in[4];
    const float* g2 = (const float*)d_in[5];
    const float* b2 = (const float*)d_in[6];
    float* out = (float*)d_out;

    // ws: y2 compact (51.4MB) at 0; stats at +56MB.
    char* ws = (char*)d_ws;
    u16*   y2c  = (u16*)ws;
    float* st   = (float*)(ws + (size_t)(56u << 20));
    float* sums1 = st, *sums2 = st + 128;
    // d_out hosts y1 half-planes + repacked weights; dead before finalize writes.
    char*  oc   = (char*)d_out;
    u16*   y1p  = (u16*)oc;                            // 53.5 MB
    u16*   wt1  = (u16*)(oc + (size_t)(54u << 20));    // 2.25 MB
    u16*   wt2  = (u16*)(oc + (size_t)(58u << 20));    // 2.25 MB

    repack2_kernel<<<9217, 256, 0, stream>>>(w1, w2, wt1, wt2, st);

    conv_mfma<0><<<512, 448, 0, stream>>>(x, nullptr, wt1, y1p, sums1, st, g1, b1);
    conv_mfma<1><<<512, 448, 0, stream>>>(nullptr, y1p, wt2, y2c, sums2, sums1, g1, b1);
    finalize_kernel<<<dim3(112, 32), 256, 0, stream>>>(y2c, sums2, g2, b2, x, out);
}

// Round 19
// 189.103 us; speedup vs baseline: 1.0659x; 1.0659x over previous
//
#include <hip/hip_runtime.h>

// B=32, C=64, H=W=112. Per-sample 3x3 convs via bf16 MFMA implicit GEMM.
// conv1 stages B directly from x (f32 NCHW gather + f2b + zero-pad mask);
// conv2 reads y1 half-planes [b][half(ci32)][slot][32ci], slot = POFF+y*113+x
// (col 112 = zero border, masked during staging).
// Conv block (448 thr = 7 waves): W staged via global_load_lds (73.7KB), one
// ci-half B window (64KB, 1024 slots, LINEAR 64B stride) in LDS; k-loop = pure
// {ds_read A, ds_read B, MFMA}. Wave = 64co x 112px (7 frags, acc[7][4]).
// r19: __launch_bounds__(448, 1) — LDS already caps us at 1 block/CU, so the
// old (448,2) 256-reg budget only prevented deep B-read pipelining. Give the
// register allocator the full 512-reg class.
#define HW   112
#define HW2  12544
#define CH   64
#define NB   32
#define PRW  113
#define NP   12655          // interior slots per sample
#define POFF 128
#define PS   13056          // slots per half-plane per sample
#define NPC  (NB*HW2)
#define TPX  784            // pixels per conv tile (= 7 rows)

using u16 = unsigned short;
typedef __attribute__((ext_vector_type(8))) short bf16x8;   // 8 bf16 = 4 VGPRs
typedef __attribute__((ext_vector_type(4))) float f32x4;

__device__ __forceinline__ float b2f(u16 u) {
    union { unsigned int i; float f; } c;
    c.i = ((unsigned int)u) << 16;
    return c.f;
}
__device__ __forceinline__ u16 f2b(float f) {
    union { float f; unsigned int i; } c;
    c.f = f;
    unsigned int x = c.i;
    x += 0x7fffu + ((x >> 16) & 1u);   // RNE
    return (u16)(x >> 16);
}

// async global->LDS, 16B per lane; l must be the WAVE-UNIFORM base
// (HW dest = base + lane*16). Drained by __syncthreads' vmcnt(0).
__device__ __forceinline__ void gl2lds(const u16* g, u16* l) {
    __builtin_amdgcn_global_load_lds(
        (const __attribute__((address_space(1))) unsigned int*)g,
        (__attribute__((address_space(3))) unsigned int*)l, 16, 0, 0);
}

// MODE 0: conv1 (input = x f32 NCHW, transpose+pad+convert fused into staging;
//                output = y1 half-planes, interior slots only)
// MODE 1: conv2 (input = y1 half-planes with BN1 affine+ReLU applied during
//                staging, pad slots masked to 0; output = COMPACT y2 [b][pix][64])
// wt: bf16 [b][half][tap][kq][co][8ci] (73728 B / sample, matches LDS layout).
template<int MODE>
__global__ __launch_bounds__(448, 1)
void conv_mfma(const float* __restrict__ xf, const u16* __restrict__ img,
               const u16* __restrict__ wt,
               u16* __restrict__ outp, float* __restrict__ sums,
               const float* __restrict__ psums, const float* __restrict__ gamma,
               const float* __restrict__ beta)
{
    __shared__ u16 wl[36864];            // 73728 B weights, both halves
    __shared__ u16 bt[32768];            // 65536 B: 1024 slots x 32ci (one half)
    // XCD swizzle: 512 = 8 x 64 -> each XCD gets 4 whole samples.
    const int bid = (int)blockIdx.x;
    const int sid = (bid & 7) * 64 + (bid >> 3);
    const int b = sid >> 4, tile = sid & 15;
    const int p0 = tile * TPX;           // first pixel of tile
    const int w0 = tile * 791 - 114;     // staged window start (slot space)
    const int tid = threadIdx.x;
    const int lane = tid & 63, wave = tid >> 6;   // wave 0..6
    const int px = lane & 15, kg = lane >> 4;
    const u16* wtb = wt + (size_t)b * 36864;

    // ---- stage ALL weights: async gllds, waves 0-5, 12 chunks each ----
    if (tid < 384) {
#pragma unroll
        for (int i = 0; i < 12; ++i) {
            const int c = i * 384 + tid;                 // 4608 chunks exact
            gl2lds(wtb + (size_t)c * 8, wl + (size_t)(c - lane) * 8);
        }
    }

    // ---- BN1 params for MODE1 staging (q = tid&3 loop-invariant: 448%4==0) ----
    float sc0[8], bi0[8], sc1[8], bi1[8];
    if (MODE == 1) {
        const int q = tid & 3;
#pragma unroll
        for (int e = 0; e < 8; ++e) {
            int c0 = q * 8 + e, c1 = 32 + q * 8 + e;
            float m0 = psums[c0] * (1.f / NPC), m1 = psums[c1] * (1.f / NPC);
            float v0 = psums[64 + c0] * (1.f / NPC) - m0 * m0;
            float v1 = psums[64 + c1] * (1.f / NPC) - m1 * m1;
            sc0[e] = gamma[c0] * rsqrtf(v0 + 1e-5f); bi0[e] = beta[c0] - m0 * sc0[e];
            sc1[e] = gamma[c1] * rsqrtf(v1 + 1e-5f); bi1[e] = beta[c1] - m1 * sc1[e];
        }
    }
    const float* xb = (MODE == 0) ? xf + (size_t)b * CH * HW2 : nullptr;

    // ---- stage B half 0 ----
    // MODE0: gather from x f32 (transpose+convert+pad fused).
    // MODE1: y1 bf16 + BN1 affine+ReLU, pads masked.
    {
        const u16* bp = img + ((size_t)(b * 2 + 0) * PS + POFF + w0) * 32;
        for (int c = tid; c < 4096; c += 448) {
            const int pt = w0 + (c >> 2);
            bf16x8 v = (bf16x8)0;
            if (MODE == 0) {
                if ((unsigned)pt < (unsigned)NP) {
                    int y  = (unsigned)pt / PRW;
                    int xc = pt - y * PRW;
                    if (xc != PRW - 1) {
                        const float* src = xb + (size_t)((c & 3) * 8) * HW2 + y * HW + xc;
#pragma unroll
                        for (int e = 0; e < 8; ++e)
                            v[e] = (short)f2b(src[(size_t)e * HW2]);
                    }
                }
            } else {
                bool val = ((unsigned)pt < (unsigned)NP) && (pt % PRW != PRW - 1);
                bf16x8 r = *(const bf16x8*)(bp + c * 8);
#pragma unroll
                for (int e = 0; e < 8; ++e) {
                    float t = b2f((u16)r[e]) * sc0[e] + bi0[e];
                    t = (val && t > 0.f) ? t : 0.f;
                    v[e] = (short)f2b(t);
                }
            }
            *(bf16x8*)(bt + c * 8) = v;
        }
    }
    __syncthreads();

    // ---- per-fragment LDS slot bases (pixel -> slot, incl. row-border skips) ----
    int lsf[7];
#pragma unroll
    for (int f = 0; f < 7; ++f) {
        const int pix = p0 + (wave * 7 + f) * 16 + px;
        lsf[f] = pix + pix / HW - w0;    // in [114, 903]; +-114 stays in [0,1023]
    }

    f32x4 acc[7][4];
#pragma unroll
    for (int f = 0; f < 7; ++f)
#pragma unroll
        for (int m = 0; m < 4; ++m) acc[f][m] = (f32x4)0.f;

    // ---- main loop: 2 ci-halves x 9 taps; pure LDS + MFMA ----
#pragma unroll
    for (int h = 0; h < 2; ++h) {
        if (h == 1) {
            __syncthreads();             // all waves done with half-0 B tile
            const u16* bp = img + ((size_t)(b * 2 + 1) * PS + POFF + w0) * 32;
            for (int c = tid; c < 4096; c += 448) {
                const int pt = w0 + (c >> 2);
                bf16x8 v = (bf16x8)0;
                if (MODE == 0) {
                    if ((unsigned)pt < (unsigned)NP) {
                        int y  = (unsigned)pt / PRW;
                        int xc = pt - y * PRW;
                        if (xc != PRW - 1) {
                            const float* src = xb + (size_t)(32 + (c & 3) * 8) * HW2 + y * HW + xc;
#pragma unroll
                            for (int e = 0; e < 8; ++e)
                                v[e] = (short)f2b(src[(size_t)e * HW2]);
                        }
                    }
                } else {
                    bool val = ((unsigned)pt < (unsigned)NP) && (pt % PRW != PRW - 1);
                    bf16x8 r = *(const bf16x8*)(bp + c * 8);
#pragma unroll
                    for (int e = 0; e < 8; ++e) {
                        float t = b2f((u16)r[e]) * sc1[e] + bi1[e];
                        t = (val && t > 0.f) ? t : 0.f;
                        v[e] = (short)f2b(t);
                    }
                }
                *(bf16x8*)(bt + c * 8) = v;
            }
            __syncthreads();
        }
#pragma unroll
        for (int tap = 0; tap < 9; ++tap) {
            const int off = (tap / 3 - 1) * PRW + (tap % 3 - 1);
            bf16x8 Af[4];
#pragma unroll
            for (int m = 0; m < 4; ++m)
                Af[m] = *(const bf16x8*)(wl + h * 18432 + tap * 2048 + kg * 512 + (m * 16 + px) * 8);
#pragma unroll
            for (int f = 0; f < 7; ++f) {
                bf16x8 Bf = *(const bf16x8*)(bt + (lsf[f] + off) * 32 + kg * 8);
#pragma unroll
                for (int m = 0; m < 4; ++m)
                    acc[f][m] = __builtin_amdgcn_mfma_f32_16x16x32_bf16(Af[m], Bf, acc[f][m], 0, 0, 0);
            }
        }
    }

    // ---- epilogue: unpredicated stores + fused BN batch-stat partials ----
    float s_[4][4], sq[4][4];
#pragma unroll
    for (int m = 0; m < 4; ++m)
#pragma unroll
        for (int q = 0; q < 4; ++q) { s_[m][q] = 0.f; sq[m][q] = 0.f; }

#pragma unroll
    for (int f = 0; f < 7; ++f) {
        const int pix  = p0 + (wave * 7 + f) * 16 + px;
        const int slot = pix + pix / HW;
#pragma unroll
        for (int m = 0; m < 4; ++m) {
            float v0 = acc[f][m][0], v1 = acc[f][m][1], v2 = acc[f][m][2], v3 = acc[f][m][3];
            s_[m][0] += v0; s_[m][1] += v1; s_[m][2] += v2; s_[m][3] += v3;
            sq[m][0] += v0 * v0; sq[m][1] += v1 * v1;
            sq[m][2] += v2 * v2; sq[m][3] += v3 * v3;
            uint2 pk;
            pk.x = ((unsigned)f2b(v1) << 16) | f2b(v0);
            pk.y = ((unsigned)f2b(v3) << 16) | f2b(v2);
            if (MODE == 0) {
                // y1 half-planes: half = m>>1, within-half co = (m&1)*16+kg*4
                u16* dst = outp + ((size_t)(b * 2 + (m >> 1)) * PS + POFF + slot) * 32
                                + (m & 1) * 16 + kg * 4;
                *(uint2*)dst = pk;
            } else {
                // compact y2 [b][pix][64]
                u16* dst = outp + ((size_t)b * HW2 + pix) * 64 + m * 16 + kg * 4;
                *(uint2*)dst = pk;
            }
        }
    }
#pragma unroll
    for (int off = 1; off < 16; off <<= 1) {
#pragma unroll
        for (int m = 0; m < 4; ++m)
#pragma unroll
            for (int q = 0; q < 4; ++q) {
                s_[m][q] += __shfl_xor(s_[m][q], off);
                sq[m][q] += __shfl_xor(sq[m][q], off);
            }
    }
    __syncthreads();                     // bt reads done; reuse as reduce buffer
    float* red = (float*)bt;             // 7 waves x 128 floats
    if (px == 0) {
#pragma unroll
        for (int m = 0; m < 4; ++m)
#pragma unroll
            for (int q = 0; q < 4; ++q) {
                int c = m * 16 + kg * 4 + q;
                red[wave * 128 + c]      = s_[m][q];
                red[wave * 128 + 64 + c] = sq[m][q];
            }
    }
    __syncthreads();
    if (tid < 128) {
        float t = 0.f;
#pragma unroll
        for (int k = 0; k < 7; ++k) t += red[k * 128 + tid];
        atomicAdd(&sums[tid], t);
    }
}

// both weights: [b][co][ci][3][3] f32 -> [b][half][tap][kq][co][8ci] bf16.
// Extra trailing block zeroes the stats area.
__global__ __launch_bounds__(256)
void repack2_kernel(const float* __restrict__ w1, const float* __restrict__ w2,
                    u16* __restrict__ wt1, u16* __restrict__ wt2,
                    float* __restrict__ st)
{
    if (blockIdx.x == 9216) {
        st[threadIdx.x] = 0.f;           // 256 floats (sums1 + sums2)
        return;
    }
    int i = blockIdx.x * 256 + threadIdx.x;      // 0..2359295
    const int N = NB * 36864;
    const float* w = (i < N) ? w1 : w2;
    u16* wt = (i < N) ? wt1 : wt2;
    int o = (i < N) ? i : i - N;
    int b = o / 36864, r = o - b * 36864;
    int half = r / 18432; r -= half * 18432;
    int tap  = r / 2048;  r -= tap * 2048;
    int kq   = r / 512;   r -= kq * 512;
    int co   = r / 8;
    int ci   = half * 32 + kq * 8 + (r & 7);
    wt[o] = f2b(w[(((size_t)b * 64 + co) * 64 + ci) * 9 + tap]);
}

// out = relu(bn2(y2) + x), NCHW f32 via LDS transpose; y2 compact [b][pix][64]
__global__ __launch_bounds__(256)
void finalize_kernel(const u16* __restrict__ y2, const float* __restrict__ sums,
                     const float* __restrict__ gamma, const float* __restrict__ beta,
                     const float* __restrict__ x, float* __restrict__ out)
{
    __shared__ float lt[64][116];
    __shared__ float sbl[128];
    const int b = blockIdx.y, y = blockIdx.x;
    const int tid = threadIdx.x;
    if (tid < 64) {
        float mean = sums[tid] * (1.f / NPC);
        float var  = sums[64 + tid] * (1.f / NPC) - mean * mean;
        float sc   = gamma[tid] * rsqrtf(var + 1e-5f);
        sbl[tid]      = sc;
        sbl[64 + tid] = beta[tid] - mean * sc;
    }
    __syncthreads();
    const u16* rowp = y2 + ((size_t)b * HW2 + (size_t)y * HW) * 64;
    {
        const int cg = tid & 7;
        float sc[8], bi[8];
#pragma unroll
        for (int e = 0; e < 8; ++e) { sc[e] = sbl[cg * 8 + e]; bi[e] = sbl[64 + cg * 8 + e]; }
        for (int t = tid; t < HW * 8; t += 256) {
            int px = t >> 3;
            bf16x8 v = *(const bf16x8*)(rowp + px * 64 + cg * 8);
#pragma unroll
            for (int e = 0; e < 8; ++e)
                lt[cg * 8 + e][px] = b2f((u16)v[e]) * sc[e] + bi[e];
        }
    }
    __syncthreads();
    {
        const int c = tid >> 2, xg = (tid & 3) * 28;
        size_t base = ((size_t)b * CH + c) * HW2 + (size_t)y * HW + xg;
#pragma unroll
        for (int i = 0; i < 7; ++i) {
            float4 xv = *(const float4*)(x + base + i * 4);
            float4 r;
            r.x = fmaxf(lt[c][xg + i * 4 + 0] + xv.x, 0.f);
            r.y = fmaxf(lt[c][xg + i * 4 + 1] + xv.y, 0.f);
            r.z = fmaxf(lt[c][xg + i * 4 + 2] + xv.z, 0.f);
            r.w = fmaxf(lt[c][xg + i * 4 + 3] + xv.w, 0.f);
            *(float4*)(out + base + i * 4) = r;
        }
    }
}

extern "C" void kernel_launch(void* const* d_in, const int* in_sizes, int n_in,
                              void* d_out, int out_size, void* d_ws, size_t ws_size,
                              hipStream_t stream)
{
    const float* x  = (const float*)d_in[0];
    const float* w1 = (const float*)d_in[1];
    const float* w2 = (const float*)d_in[2];
    const float* g1 = (const float*)d_in[3];
    const float* b1 = (const float*)d_in[4];
    const float* g2 = (const float*)d_in[5];
    const float* b2 = (const float*)d_in[6];
    float* out = (float*)d_out;

    // ws: y2 compact (51.4MB) at 0; stats at +56MB.
    char* ws = (char*)d_ws;
    u16*   y2c  = (u16*)ws;
    float* st   = (float*)(ws + (size_t)(56u << 20));
    float* sums1 = st, *sums2 = st + 128;
    // d_out hosts y1 half-planes + repacked weights; dead before finalize writes.
    char*  oc   = (char*)d_out;
    u16*   y1p  = (u16*)oc;                            // 53.5 MB
    u16*   wt1  = (u16*)(oc + (size_t)(54u << 20));    // 2.25 MB
    u16*   wt2  = (u16*)(oc + (size_t)(58u << 20));    // 2.25 MB

    repack2_kernel<<<9217, 256, 0, stream>>>(w1, w2, wt1, wt2, st);

    conv_mfma<0><<<512, 448, 0, stream>>>(x, nullptr, wt1, y1p, sums1, st, g1, b1);
    conv_mfma<1><<<512, 448, 0, stream>>>(nullptr, y1p, wt2, y2c, sums2, sums1, g1, b1);
    finalize_kernel<<<dim3(112, 32), 256, 0, stream>>>(y2c, sums2, g2, b2, x, out);
}

// Round 20
// 182.110 us; speedup vs baseline: 1.1069x; 1.0384x over previous
//
#include <hip/hip_runtime.h>

// B=32, C=64, H=W=112. Per-sample 3x3 convs via bf16 MFMA implicit GEMM.
// conv1 stages B directly from x (f32 NCHW gather + f2b + zero-pad mask);
// conv2 reads y1 half-planes [b][half(ci32)][slot][32ci], slot = POFF+y*113+x
// (col 112 = zero border, masked during staging).
// Conv block (448 thr = 7 waves): W staged via global_load_lds (73.7KB), one
// ci-half B window (64KB, 1024 slots, LINEAR 64B stride) in LDS; k-loop = pure
// {ds_read A, ds_read B, MFMA}. Wave = 64co x 112px (7 frags, acc[7][4]).
// r20: staging loops EXACT-TRIP UNROLLED (9 x 448 + 64-thread tail = 4096) so
// the compiler can put all ~72 staging loads in flight before the converts —
// the old dynamic-bound loop serialized ~9 long-latency load iterations.
#define HW   112
#define HW2  12544
#define CH   64
#define NB   32
#define PRW  113
#define NP   12655          // interior slots per sample
#define POFF 128
#define PS   13056          // slots per half-plane per sample
#define NPC  (NB*HW2)
#define TPX  784            // pixels per conv tile (= 7 rows)

using u16 = unsigned short;
typedef __attribute__((ext_vector_type(8))) short bf16x8;   // 8 bf16 = 4 VGPRs
typedef __attribute__((ext_vector_type(4))) float f32x4;

__device__ __forceinline__ float b2f(u16 u) {
    union { unsigned int i; float f; } c;
    c.i = ((unsigned int)u) << 16;
    return c.f;
}
__device__ __forceinline__ u16 f2b(float f) {
    union { float f; unsigned int i; } c;
    c.f = f;
    unsigned int x = c.i;
    x += 0x7fffu + ((x >> 16) & 1u);   // RNE
    return (u16)(x >> 16);
}

// async global->LDS, 16B per lane; l must be the WAVE-UNIFORM base
// (HW dest = base + lane*16). Drained by __syncthreads' vmcnt(0).
__device__ __forceinline__ void gl2lds(const u16* g, u16* l) {
    __builtin_amdgcn_global_load_lds(
        (const __attribute__((address_space(1))) unsigned int*)g,
        (__attribute__((address_space(3))) unsigned int*)l, 16, 0, 0);
}

// MODE 0: conv1 (input = x f32 NCHW, transpose+pad+convert fused into staging;
//                output = y1 half-planes, interior slots only)
// MODE 1: conv2 (input = y1 half-planes with BN1 affine+ReLU applied during
//                staging, pad slots masked to 0; output = COMPACT y2 [b][pix][64])
// wt: bf16 [b][half][tap][kq][co][8ci] (73728 B / sample, matches LDS layout).
template<int MODE>
__global__ __launch_bounds__(448, 1)
void conv_mfma(const float* __restrict__ xf, const u16* __restrict__ img,
               const u16* __restrict__ wt,
               u16* __restrict__ outp, float* __restrict__ sums,
               const float* __restrict__ psums, const float* __restrict__ gamma,
               const float* __restrict__ beta)
{
    __shared__ u16 wl[36864];            // 73728 B weights, both halves
    __shared__ u16 bt[32768];            // 65536 B: 1024 slots x 32ci (one half)
    // XCD swizzle: 512 = 8 x 64 -> each XCD gets 4 whole samples.
    const int bid = (int)blockIdx.x;
    const int sid = (bid & 7) * 64 + (bid >> 3);
    const int b = sid >> 4, tile = sid & 15;
    const int p0 = tile * TPX;           // first pixel of tile
    const int w0 = tile * 791 - 114;     // staged window start (slot space)
    const int tid = threadIdx.x;
    const int lane = tid & 63, wave = tid >> 6;   // wave 0..6
    const int px = lane & 15, kg = lane >> 4;
    const u16* wtb = wt + (size_t)b * 36864;

    // ---- stage ALL weights: async gllds, waves 0-5, 12 chunks each ----
    if (tid < 384) {
#pragma unroll
        for (int i = 0; i < 12; ++i) {
            const int c = i * 384 + tid;                 // 4608 chunks exact
            gl2lds(wtb + (size_t)c * 8, wl + (size_t)(c - lane) * 8);
        }
    }

    // ---- BN1 params for MODE1 staging (q = tid&3 loop-invariant: 448%4==0) ----
    float sc0[8], bi0[8], sc1[8], bi1[8];
    if (MODE == 1) {
        const int q = tid & 3;
#pragma unroll
        for (int e = 0; e < 8; ++e) {
            int c0 = q * 8 + e, c1 = 32 + q * 8 + e;
            float m0 = psums[c0] * (1.f / NPC), m1 = psums[c1] * (1.f / NPC);
            float v0 = psums[64 + c0] * (1.f / NPC) - m0 * m0;
            float v1 = psums[64 + c1] * (1.f / NPC) - m1 * m1;
            sc0[e] = gamma[c0] * rsqrtf(v0 + 1e-5f); bi0[e] = beta[c0] - m0 * sc0[e];
            sc1[e] = gamma[c1] * rsqrtf(v1 + 1e-5f); bi1[e] = beta[c1] - m1 * sc1[e];
        }
    }
    const float* xb = (MODE == 0) ? xf + (size_t)b * CH * HW2 : nullptr;

    // ---- stage B half 0 (exact-trip unrolled: 9 x 448 + 64 tail) ----
    {
        const u16* bp = img + ((size_t)(b * 2 + 0) * PS + POFF + w0) * 32;
        auto st0 = [&](int c) {
            const int pt = w0 + (c >> 2);
            bf16x8 v = (bf16x8)0;
            if (MODE == 0) {
                if ((unsigned)pt < (unsigned)NP) {
                    int y  = (unsigned)pt / PRW;
                    int xc = pt - y * PRW;
                    if (xc != PRW - 1) {
                        const float* src = xb + (size_t)((c & 3) * 8) * HW2 + y * HW + xc;
#pragma unroll
                        for (int e = 0; e < 8; ++e)
                            v[e] = (short)f2b(src[(size_t)e * HW2]);
                    }
                }
            } else {
                bool val = ((unsigned)pt < (unsigned)NP) && (pt % PRW != PRW - 1);
                bf16x8 r = *(const bf16x8*)(bp + c * 8);
#pragma unroll
                for (int e = 0; e < 8; ++e) {
                    float t = b2f((u16)r[e]) * sc0[e] + bi0[e];
                    t = (val && t > 0.f) ? t : 0.f;
                    v[e] = (short)f2b(t);
                }
            }
            *(bf16x8*)(bt + c * 8) = v;
        };
#pragma unroll
        for (int i = 0; i < 9; ++i) st0(i * 448 + tid);
        if (tid < 64) st0(4032 + tid);
    }
    __syncthreads();

    // ---- per-fragment LDS slot bases (pixel -> slot, incl. row-border skips) ----
    int lsf[7];
#pragma unroll
    for (int f = 0; f < 7; ++f) {
        const int pix = p0 + (wave * 7 + f) * 16 + px;
        lsf[f] = pix + pix / HW - w0;    // in [114, 903]; +-114 stays in [0,1023]
    }

    f32x4 acc[7][4];
#pragma unroll
    for (int f = 0; f < 7; ++f)
#pragma unroll
        for (int m = 0; m < 4; ++m) acc[f][m] = (f32x4)0.f;

    // ---- main loop: 2 ci-halves x 9 taps; pure LDS + MFMA ----
#pragma unroll
    for (int h = 0; h < 2; ++h) {
        if (h == 1) {
            __syncthreads();             // all waves done with half-0 B tile
            const u16* bp = img + ((size_t)(b * 2 + 1) * PS + POFF + w0) * 32;
            auto st1 = [&](int c) {
                const int pt = w0 + (c >> 2);
                bf16x8 v = (bf16x8)0;
                if (MODE == 0) {
                    if ((unsigned)pt < (unsigned)NP) {
                        int y  = (unsigned)pt / PRW;
                        int xc = pt - y * PRW;
                        if (xc != PRW - 1) {
                            const float* src = xb + (size_t)(32 + (c & 3) * 8) * HW2 + y * HW + xc;
#pragma unroll
                            for (int e = 0; e < 8; ++e)
                                v[e] = (short)f2b(src[(size_t)e * HW2]);
                        }
                    }
                } else {
                    bool val = ((unsigned)pt < (unsigned)NP) && (pt % PRW != PRW - 1);
                    bf16x8 r = *(const bf16x8*)(bp + c * 8);
#pragma unroll
                    for (int e = 0; e < 8; ++e) {
                        float t = b2f((u16)r[e]) * sc1[e] + bi1[e];
                        t = (val && t > 0.f) ? t : 0.f;
                        v[e] = (short)f2b(t);
                    }
                }
                *(bf16x8*)(bt + c * 8) = v;
            };
#pragma unroll
            for (int i = 0; i < 9; ++i) st1(i * 448 + tid);
            if (tid < 64) st1(4032 + tid);
            __syncthreads();
        }
#pragma unroll
        for (int tap = 0; tap < 9; ++tap) {
            const int off = (tap / 3 - 1) * PRW + (tap % 3 - 1);
            bf16x8 Af[4];
#pragma unroll
            for (int m = 0; m < 4; ++m)
                Af[m] = *(const bf16x8*)(wl + h * 18432 + tap * 2048 + kg * 512 + (m * 16 + px) * 8);
#pragma unroll
            for (int f = 0; f < 7; ++f) {
                bf16x8 Bf = *(const bf16x8*)(bt + (lsf[f] + off) * 32 + kg * 8);
#pragma unroll
                for (int m = 0; m < 4; ++m)
                    acc[f][m] = __builtin_amdgcn_mfma_f32_16x16x32_bf16(Af[m], Bf, acc[f][m], 0, 0, 0);
            }
        }
    }

    // ---- epilogue: unpredicated stores + fused BN batch-stat partials ----
    float s_[4][4], sq[4][4];
#pragma unroll
    for (int m = 0; m < 4; ++m)
#pragma unroll
        for (int q = 0; q < 4; ++q) { s_[m][q] = 0.f; sq[m][q] = 0.f; }

#pragma unroll
    for (int f = 0; f < 7; ++f) {
        const int pix  = p0 + (wave * 7 + f) * 16 + px;
        const int slot = pix + pix / HW;
#pragma unroll
        for (int m = 0; m < 4; ++m) {
            float v0 = acc[f][m][0], v1 = acc[f][m][1], v2 = acc[f][m][2], v3 = acc[f][m][3];
            s_[m][0] += v0; s_[m][1] += v1; s_[m][2] += v2; s_[m][3] += v3;
            sq[m][0] += v0 * v0; sq[m][1] += v1 * v1;
            sq[m][2] += v2 * v2; sq[m][3] += v3 * v3;
            uint2 pk;
            pk.x = ((unsigned)f2b(v1) << 16) | f2b(v0);
            pk.y = ((unsigned)f2b(v3) << 16) | f2b(v2);
            if (MODE == 0) {
                // y1 half-planes: half = m>>1, within-half co = (m&1)*16+kg*4
                u16* dst = outp + ((size_t)(b * 2 + (m >> 1)) * PS + POFF + slot) * 32
                                + (m & 1) * 16 + kg * 4;
                *(uint2*)dst = pk;
            } else {
                // compact y2 [b][pix][64]
                u16* dst = outp + ((size_t)b * HW2 + pix) * 64 + m * 16 + kg * 4;
                *(uint2*)dst = pk;
            }
        }
    }
#pragma unroll
    for (int off = 1; off < 16; off <<= 1) {
#pragma unroll
        for (int m = 0; m < 4; ++m)
#pragma unroll
            for (int q = 0; q < 4; ++q) {
                s_[m][q] += __shfl_xor(s_[m][q], off);
                sq[m][q] += __shfl_xor(sq[m][q], off);
            }
    }
    __syncthreads();                     // bt reads done; reuse as reduce buffer
    float* red = (float*)bt;             // 7 waves x 128 floats
    if (px == 0) {
#pragma unroll
        for (int m = 0; m < 4; ++m)
#pragma unroll
            for (int q = 0; q < 4; ++q) {
                int c = m * 16 + kg * 4 + q;
                red[wave * 128 + c]      = s_[m][q];
                red[wave * 128 + 64 + c] = sq[m][q];
            }
    }
    __syncthreads();
    if (tid < 128) {
        float t = 0.f;
#pragma unroll
        for (int k = 0; k < 7; ++k) t += red[k * 128 + tid];
        atomicAdd(&sums[tid], t);
    }
}

// both weights: [b][co][ci][3][3] f32 -> [b][half][tap][kq][co][8ci] bf16.
// Extra trailing block zeroes the stats area.
__global__ __launch_bounds__(256)
void repack2_kernel(const float* __restrict__ w1, const float* __restrict__ w2,
                    u16* __restrict__ wt1, u16* __restrict__ wt2,
                    float* __restrict__ st)
{
    if (blockIdx.x == 9216) {
        st[threadIdx.x] = 0.f;           // 256 floats (sums1 + sums2)
        return;
    }
    int i = blockIdx.x * 256 + threadIdx.x;      // 0..2359295
    const int N = NB * 36864;
    const float* w = (i < N) ? w1 : w2;
    u16* wt = (i < N) ? wt1 : wt2;
    int o = (i < N) ? i : i - N;
    int b = o / 36864, r = o - b * 36864;
    int half = r / 18432; r -= half * 18432;
    int tap  = r / 2048;  r -= tap * 2048;
    int kq   = r / 512;   r -= kq * 512;
    int co   = r / 8;
    int ci   = half * 32 + kq * 8 + (r & 7);
    wt[o] = f2b(w[(((size_t)b * 64 + co) * 64 + ci) * 9 + tap]);
}

// out = relu(bn2(y2) + x), NCHW f32 via LDS transpose; y2 compact [b][pix][64]
__global__ __launch_bounds__(256)
void finalize_kernel(const u16* __restrict__ y2, const float* __restrict__ sums,
                     const float* __restrict__ gamma, const float* __restrict__ beta,
                     const float* __restrict__ x, float* __restrict__ out)
{
    __shared__ float lt[64][116];
    __shared__ float sbl[128];
    const int b = blockIdx.y, y = blockIdx.x;
    const int tid = threadIdx.x;
    if (tid < 64) {
        float mean = sums[tid] * (1.f / NPC);
        float var  = sums[64 + tid] * (1.f / NPC) - mean * mean;
        float sc   = gamma[tid] * rsqrtf(var + 1e-5f);
        sbl[tid]      = sc;
        sbl[64 + tid] = beta[tid] - mean * sc;
    }
    __syncthreads();
    const u16* rowp = y2 + ((size_t)b * HW2 + (size_t)y * HW) * 64;
    {
        const int cg = tid & 7;
        float sc[8], bi[8];
#pragma unroll
        for (int e = 0; e < 8; ++e) { sc[e] = sbl[cg * 8 + e]; bi[e] = sbl[64 + cg * 8 + e]; }
        for (int t = tid; t < HW * 8; t += 256) {
            int px = t >> 3;
            bf16x8 v = *(const bf16x8*)(rowp + px * 64 + cg * 8);
#pragma unroll
            for (int e = 0; e < 8; ++e)
                lt[cg * 8 + e][px] = b2f((u16)v[e]) * sc[e] + bi[e];
        }
    }
    __syncthreads();
    {
        const int c = tid >> 2, xg = (tid & 3) * 28;
        size_t base = ((size_t)b * CH + c) * HW2 + (size_t)y * HW + xg;
#pragma unroll
        for (int i = 0; i < 7; ++i) {
            float4 xv = *(const float4*)(x + base + i * 4);
            float4 r;
            r.x = fmaxf(lt[c][xg + i * 4 + 0] + xv.x, 0.f);
            r.y = fmaxf(lt[c][xg + i * 4 + 1] + xv.y, 0.f);
            r.z = fmaxf(lt[c][xg + i * 4 + 2] + xv.z, 0.f);
            r.w = fmaxf(lt[c][xg + i * 4 + 3] + xv.w, 0.f);
            *(float4*)(out + base + i * 4) = r;
        }
    }
}

extern "C" void kernel_launch(void* const* d_in, const int* in_sizes, int n_in,
                              void* d_out, int out_size, void* d_ws, size_t ws_size,
                              hipStream_t stream)
{
    const float* x  = (const float*)d_in[0];
    const float* w1 = (const float*)d_in[1];
    const float* w2 = (const float*)d_in[2];
    const float* g1 = (const float*)d_in[3];
    const float* b1 = (const float*)d_in[4];
    const float* g2 = (const float*)d_in[5];
    const float* b2 = (const float*)d_in[6];
    float* out = (float*)d_out;

    // ws: y2 compact (51.4MB) at 0; stats at +56MB.
    char* ws = (char*)d_ws;
    u16*   y2c  = (u16*)ws;
    float* st   = (float*)(ws + (size_t)(56u << 20));
    float* sums1 = st, *sums2 = st + 128;
    // d_out hosts y1 half-planes + repacked weights; dead before finalize writes.
    char*  oc   = (char*)d_out;
    u16*   y1p  = (u16*)oc;                            // 53.5 MB
    u16*   wt1  = (u16*)(oc + (size_t)(54u << 20));    // 2.25 MB
    u16*   wt2  = (u16*)(oc + (size_t)(58u << 20));    // 2.25 MB

    repack2_kernel<<<9217, 256, 0, stream>>>(w1, w2, wt1, wt2, st);

    conv_mfma<0><<<512, 448, 0, stream>>>(x, nullptr, wt1, y1p, sums1, st, g1, b1);
    conv_mfma<1><<<512, 448, 0, stream>>>(nullptr, y1p, wt2, y2c, sums2, sums1, g1, b1);
    finalize_kernel<<<dim3(112, 32), 256, 0, stream>>>(y2c, sums2, g2, b2, x, out);
}

// Round 21
// 180.211 us; speedup vs baseline: 1.1185x; 1.0105x over previous
//
#include <hip/hip_runtime.h>
#include <hip/hip_bf16.h>

// B=32, C=64, H=W=112. Per-sample 3x3 convs via bf16 MFMA implicit GEMM.
// conv1 stages B directly from x via PIXEL-SPACE dwordx4 gather (4 consecutive
// pixels are contiguous in an NCHW channel plane) + in-register transpose +
// cvt_pk; border/pad slots zeroed by a tiny window scan (disjoint writes).
// conv2 reads y1 half-planes [b][half(ci32)][slot][32ci], slot = POFF+y*113+x.
// Conv block (448 thr = 7 waves): W staged via global_load_lds (73.7KB), one
// ci-half B window (64KB, 1024 slots, LINEAR 64B stride) in LDS; k-loop = pure
// {ds_read A, ds_read B, MFMA}. Wave = 64co x 112px (7 frags, acc[7][4]).
#define HW   112
#define HW2  12544
#define CH   64
#define NB   32
#define PRW  113
#define NP   12655          // interior slots per sample
#define POFF 128
#define PS   13056          // slots per half-plane per sample
#define NPC  (NB*HW2)
#define TPX  784            // pixels per conv tile (= 7 rows)

using u16 = unsigned short;
typedef __attribute__((ext_vector_type(8))) short bf16x8;   // 8 bf16 = 4 VGPRs
typedef __attribute__((ext_vector_type(4))) float f32x4;

__device__ __forceinline__ float b2f(u16 u) {
    union { unsigned int i; float f; } c;
    c.i = ((unsigned int)u) << 16;
    return c.f;
}
__device__ __forceinline__ u16 f2b(float f) {
    union { float f; unsigned int i; } c;
    c.f = f;
    unsigned int x = c.i;
    x += 0x7fffu + ((x >> 16) & 1u);   // RNE
    return (u16)(x >> 16);
}
// pair f32 -> packed bf16x2 (RNE) via v_cvt_pk_bf16_f32; a = low, b = high
__device__ __forceinline__ unsigned pk2(float a, float b) {
    __hip_bfloat162 h = __float22bfloat162_rn(float2{a, b});
    union { __hip_bfloat162 h; unsigned u; } c; c.h = h; return c.u;
}

// async global->LDS, 16B per lane; l must be the WAVE-UNIFORM base
// (HW dest = base + lane*16). Drained by __syncthreads' vmcnt(0).
__device__ __forceinline__ void gl2lds(const u16* g, u16* l) {
    __builtin_amdgcn_global_load_lds(
        (const __attribute__((address_space(1))) unsigned int*)g,
        (__attribute__((address_space(3))) unsigned int*)l, 16, 0, 0);
}

// MODE 0: conv1 (input = x f32 NCHW, transpose+pad+convert fused into staging;
//                output = y1 half-planes, interior slots only)
// MODE 1: conv2 (input = y1 half-planes with BN1 affine+ReLU applied during
//                staging, pad slots masked to 0; output = COMPACT y2 [b][pix][64])
// wt: bf16 [b][half][tap][kq][co][8ci] (73728 B / sample, matches LDS layout).
template<int MODE>
__global__ __launch_bounds__(448, 1)
void conv_mfma(const float* __restrict__ xf, const u16* __restrict__ img,
               const u16* __restrict__ wt,
               u16* __restrict__ outp, float* __restrict__ sums,
               const float* __restrict__ psums, const float* __restrict__ gamma,
               const float* __restrict__ beta)
{
    __shared__ u16 wl[36864];            // 73728 B weights, both halves
    __shared__ u16 bt[32768];            // 65536 B: 1024 slots x 32ci (one half)
    // XCD swizzle: 512 = 8 x 64 -> each XCD gets 4 whole samples.
    const int bid = (int)blockIdx.x;
    const int sid = (bid & 7) * 64 + (bid >> 3);
    const int b = sid >> 4, tile = sid & 15;
    const int p0 = tile * TPX;           // first pixel of tile
    const int w0 = tile * 791 - 114;     // staged window start (slot space)
    const int tid = threadIdx.x;
    const int lane = tid & 63, wave = tid >> 6;   // wave 0..6
    const int px = lane & 15, kg = lane >> 4;
    const u16* wtb = wt + (size_t)b * 36864;

    // ---- stage ALL weights: async gllds, waves 0-5, 12 chunks each ----
    if (tid < 384) {
#pragma unroll
        for (int i = 0; i < 12; ++i) {
            const int c = i * 384 + tid;                 // 4608 chunks exact
            gl2lds(wtb + (size_t)c * 8, wl + (size_t)(c - lane) * 8);
        }
    }

    // ---- BN1 params for MODE1 staging (q = tid&3 loop-invariant: 448%4==0) ----
    float sc0[8], bi0[8], sc1[8], bi1[8];
    if (MODE == 1) {
        const int q = tid & 3;
#pragma unroll
        for (int e = 0; e < 8; ++e) {
            int c0 = q * 8 + e, c1 = 32 + q * 8 + e;
            float m0 = psums[c0] * (1.f / NPC), m1 = psums[c1] * (1.f / NPC);
            float v0 = psums[64 + c0] * (1.f / NPC) - m0 * m0;
            float v1 = psums[64 + c1] * (1.f / NPC) - m1 * m1;
            sc0[e] = gamma[c0] * rsqrtf(v0 + 1e-5f); bi0[e] = beta[c0] - m0 * sc0[e];
            sc1[e] = gamma[c1] * rsqrtf(v1 + 1e-5f); bi1[e] = beta[c1] - m1 * sc1[e];
        }
    }
    const float* xb = (MODE == 0) ? xf + (size_t)b * CH * HW2 : nullptr;

    // pixel window start for MODE0 gather (4-aligned)
    int pl4 = 0;
    if (MODE == 0) {
        int pl = w0 - w0 / PRW;          // first pixel at/after slot w0
        if (pl < 0) pl = 0;
        pl4 = pl & ~3;
    }

    // MODE0 pixel-fill: 8 dwordx4 loads + transpose-pack + 4 b128 LDS writes.
    auto pfill = [&](int task, int h) {
        const int unit = task >> 2, oct = task & 3;
        const int p_base = pl4 + unit * 4;
        const float* pp = xb + (size_t)(h * 32 + oct * 8) * HW2 + p_base;
        f32x4 q[8];
        if (p_base <= HW2 - 4) {
#pragma unroll
            for (int e = 0; e < 8; ++e) q[e] = *(const f32x4*)(pp + (size_t)e * HW2);
        } else {
#pragma unroll
            for (int e = 0; e < 8; ++e) {
                q[e] = (f32x4)0.f;
#pragma unroll
                for (int j = 0; j < 4; ++j)
                    if (p_base + j < HW2) q[e][j] = pp[(size_t)e * HW2 + j];
            }
        }
#pragma unroll
        for (int j = 0; j < 4; ++j) {
            const int p   = p_base + j;
            const int off = p + p / HW - w0;
            if ((unsigned)off < 1018u) {
                uint4 u;
                u.x = pk2(q[0][j], q[1][j]);
                u.y = pk2(q[2][j], q[3][j]);
                u.z = pk2(q[4][j], q[5][j]);
                u.w = pk2(q[6][j], q[7][j]);
                *(uint4*)(bt + off * 32 + oct * 8) = u;
            }
        }
    };

    // ---- stage B half 0 ----
    if (MODE == 0) {
        // zero-scan: lead/trail pads + border columns in the window (once; h=1
        // pixel-fill never touches these slots, so zeros persist).
#pragma unroll
        for (int i = 0; i < 3; ++i) {
            const int s = i * 448 + tid;
            if (s < 1018) {
                const int a = w0 + s;
                if (a < 0 || a >= NP || ((a + 226) % PRW) == PRW - 1) {
                    uint4 z = {0u, 0u, 0u, 0u};
#pragma unroll
                    for (int k = 0; k < 4; ++k) *(uint4*)(bt + s * 32 + k * 8) = z;
                }
            }
        }
#pragma unroll
        for (int i = 0; i < 2; ++i) pfill(i * 448 + tid, 0);
        if (tid < 120) pfill(896 + tid, 0);
    } else {
        const u16* bp = img + ((size_t)(b * 2 + 0) * PS + POFF + w0) * 32;
        auto st0 = [&](int c) {
            const int pt = w0 + (c >> 2);
            bf16x8 v = (bf16x8)0;
            bool val = ((unsigned)pt < (unsigned)NP) && (pt % PRW != PRW - 1);
            bf16x8 r = *(const bf16x8*)(bp + c * 8);
#pragma unroll
            for (int e = 0; e < 8; ++e) {
                float t = b2f((u16)r[e]) * sc0[e] + bi0[e];
                t = (val && t > 0.f) ? t : 0.f;
                v[e] = (short)f2b(t);
            }
            *(bf16x8*)(bt + c * 8) = v;
        };
#pragma unroll
        for (int i = 0; i < 9; ++i) st0(i * 448 + tid);
        if (tid < 64) st0(4032 + tid);
    }
    __syncthreads();

    // ---- per-fragment LDS slot bases (pixel -> slot, incl. row-border skips) ----
    int lsf[7];
#pragma unroll
    for (int f = 0; f < 7; ++f) {
        const int pix = p0 + (wave * 7 + f) * 16 + px;
        lsf[f] = pix + pix / HW - w0;    // in [114, 903]; +-114 stays in [0,1023]
    }

    f32x4 acc[7][4];
#pragma unroll
    for (int f = 0; f < 7; ++f)
#pragma unroll
        for (int m = 0; m < 4; ++m) acc[f][m] = (f32x4)0.f;

    // ---- main loop: 2 ci-halves x 9 taps; pure LDS + MFMA ----
#pragma unroll
    for (int h = 0; h < 2; ++h) {
        if (h == 1) {
            __syncthreads();             // all waves done with half-0 B tile
            if (MODE == 0) {
#pragma unroll
                for (int i = 0; i < 2; ++i) pfill(i * 448 + tid, 1);
                if (tid < 120) pfill(896 + tid, 1);
            } else {
                const u16* bp = img + ((size_t)(b * 2 + 1) * PS + POFF + w0) * 32;
                auto st1 = [&](int c) {
                    const int pt = w0 + (c >> 2);
                    bf16x8 v = (bf16x8)0;
                    bool val = ((unsigned)pt < (unsigned)NP) && (pt % PRW != PRW - 1);
                    bf16x8 r = *(const bf16x8*)(bp + c * 8);
#pragma unroll
                    for (int e = 0; e < 8; ++e) {
                        float t = b2f((u16)r[e]) * sc1[e] + bi1[e];
                        t = (val && t > 0.f) ? t : 0.f;
                        v[e] = (short)f2b(t);
                    }
                    *(bf16x8*)(bt + c * 8) = v;
                };
#pragma unroll
                for (int i = 0; i < 9; ++i) st1(i * 448 + tid);
                if (tid < 64) st1(4032 + tid);
            }
            __syncthreads();
        }
#pragma unroll
        for (int tap = 0; tap < 9; ++tap) {
            const int off = (tap / 3 - 1) * PRW + (tap % 3 - 1);
            bf16x8 Af[4];
#pragma unroll
            for (int m = 0; m < 4; ++m)
                Af[m] = *(const bf16x8*)(wl + h * 18432 + tap * 2048 + kg * 512 + (m * 16 + px) * 8);
#pragma unroll
            for (int f = 0; f < 7; ++f) {
                bf16x8 Bf = *(const bf16x8*)(bt + (lsf[f] + off) * 32 + kg * 8);
#pragma unroll
                for (int m = 0; m < 4; ++m)
                    acc[f][m] = __builtin_amdgcn_mfma_f32_16x16x32_bf16(Af[m], Bf, acc[f][m], 0, 0, 0);
            }
        }
    }

    // ---- epilogue: unpredicated stores + fused BN batch-stat partials ----
    float s_[4][4], sq[4][4];
#pragma unroll
    for (int m = 0; m < 4; ++m)
#pragma unroll
        for (int q = 0; q < 4; ++q) { s_[m][q] = 0.f; sq[m][q] = 0.f; }

#pragma unroll
    for (int f = 0; f < 7; ++f) {
        const int pix  = p0 + (wave * 7 + f) * 16 + px;
        const int slot = pix + pix / HW;
#pragma unroll
        for (int m = 0; m < 4; ++m) {
            float v0 = acc[f][m][0], v1 = acc[f][m][1], v2 = acc[f][m][2], v3 = acc[f][m][3];
            s_[m][0] += v0; s_[m][1] += v1; s_[m][2] += v2; s_[m][3] += v3;
            sq[m][0] += v0 * v0; sq[m][1] += v1 * v1;
            sq[m][2] += v2 * v2; sq[m][3] += v3 * v3;
            uint2 pk;
            pk.x = ((unsigned)f2b(v1) << 16) | f2b(v0);
            pk.y = ((unsigned)f2b(v3) << 16) | f2b(v2);
            if (MODE == 0) {
                // y1 half-planes: half = m>>1, within-half co = (m&1)*16+kg*4
                u16* dst = outp + ((size_t)(b * 2 + (m >> 1)) * PS + POFF + slot) * 32
                                + (m & 1) * 16 + kg * 4;
                *(uint2*)dst = pk;
            } else {
                // compact y2 [b][pix][64]
                u16* dst = outp + ((size_t)b * HW2 + pix) * 64 + m * 16 + kg * 4;
                *(uint2*)dst = pk;
            }
        }
    }
#pragma unroll
    for (int off = 1; off < 16; off <<= 1) {
#pragma unroll
        for (int m = 0; m < 4; ++m)
#pragma unroll
            for (int q = 0; q < 4; ++q) {
                s_[m][q] += __shfl_xor(s_[m][q], off);
                sq[m][q] += __shfl_xor(sq[m][q], off);
            }
    }
    __syncthreads();                     // bt reads done; reuse as reduce buffer
    float* red = (float*)bt;             // 7 waves x 128 floats
    if (px == 0) {
#pragma unroll
        for (int m = 0; m < 4; ++m)
#pragma unroll
            for (int q = 0; q < 4; ++q) {
                int c = m * 16 + kg * 4 + q;
                red[wave * 128 + c]      = s_[m][q];
                red[wave * 128 + 64 + c] = sq[m][q];
            }
    }
    __syncthreads();
    if (tid < 128) {
        float t = 0.f;
#pragma unroll
        for (int k = 0; k < 7; ++k) t += red[k * 128 + tid];
        atomicAdd(&sums[tid], t);
    }
}

// both weights: [b][co][ci][3][3] f32 -> [b][half][tap][kq][co][8ci] bf16.
// Extra trailing block zeroes the stats area.
__global__ __launch_bounds__(256)
void repack2_kernel(const float* __restrict__ w1, const float* __restrict__ w2,
                    u16* __restrict__ wt1, u16* __restrict__ wt2,
                    float* __restrict__ st)
{
    if (blockIdx.x == 9216) {
        st[threadIdx.x] = 0.f;           // 256 floats (sums1 + sums2)
        return;
    }
    int i = blockIdx.x * 256 + threadIdx.x;      // 0..2359295
    const int N = NB * 36864;
    const float* w = (i < N) ? w1 : w2;
    u16* wt = (i < N) ? wt1 : wt2;
    int o = (i < N) ? i : i - N;
    int b = o / 36864, r = o - b * 36864;
    int half = r / 18432; r -= half * 18432;
    int tap  = r / 2048;  r -= tap * 2048;
    int kq   = r / 512;   r -= kq * 512;
    int co   = r / 8;
    int ci   = half * 32 + kq * 8 + (r & 7);
    wt[o] = f2b(w[(((size_t)b * 64 + co) * 64 + ci) * 9 + tap]);
}

// out = relu(bn2(y2) + x), NCHW f32 via LDS transpose; y2 compact [b][pix][64]
__global__ __launch_bounds__(256)
void finalize_kernel(const u16* __restrict__ y2, const float* __restrict__ sums,
                     const float* __restrict__ gamma, const float* __restrict__ beta,
                     const float* __restrict__ x, float* __restrict__ out)
{
    __shared__ float lt[64][116];
    __shared__ float sbl[128];
    const int b = blockIdx.y, y = blockIdx.x;
    const int tid = threadIdx.x;
    if (tid < 64) {
        float mean = sums[tid] * (1.f / NPC);
        float var  = sums[64 + tid] * (1.f / NPC) - mean * mean;
        float sc   = gamma[tid] * rsqrtf(var + 1e-5f);
        sbl[tid]      = sc;
        sbl[64 + tid] = beta[tid] - mean * sc;
    }
    __syncthreads();
    const u16* rowp = y2 + ((size_t)b * HW2 + (size_t)y * HW) * 64;
    {
        const int cg = tid & 7;
        float sc[8], bi[8];
#pragma unroll
        for (int e = 0; e < 8; ++e) { sc[e] = sbl[cg * 8 + e]; bi[e] = sbl[64 + cg * 8 + e]; }
        for (int t = tid; t < HW * 8; t += 256) {
            int px = t >> 3;
            bf16x8 v = *(const bf16x8*)(rowp + px * 64 + cg * 8);
#pragma unroll
            for (int e = 0; e < 8; ++e)
                lt[cg * 8 + e][px] = b2f((u16)v[e]) * sc[e] + bi[e];
        }
    }
    __syncthreads();
    {
        const int c = tid >> 2, xg = (tid & 3) * 28;
        size_t base = ((size_t)b * CH + c) * HW2 + (size_t)y * HW + xg;
#pragma unroll
        for (int i = 0; i < 7; ++i) {
            float4 xv = *(const float4*)(x + base + i * 4);
            float4 r;
            r.x = fmaxf(lt[c][xg + i * 4 + 0] + xv.x, 0.f);
            r.y = fmaxf(lt[c][xg + i * 4 + 1] + xv.y, 0.f);
            r.z = fmaxf(lt[c][xg + i * 4 + 2] + xv.z, 0.f);
            r.w = fmaxf(lt[c][xg + i * 4 + 3] + xv.w, 0.f);
            *(float4*)(out + base + i * 4) = r;
        }
    }
}

extern "C" void kernel_launch(void* const* d_in, const int* in_sizes, int n_in,
                              void* d_out, int out_size, void* d_ws, size_t ws_size,
                              hipStream_t stream)
{
    const float* x  = (const float*)d_in[0];
    const float* w1 = (const float*)d_in[1];
    const float* w2 = (const float*)d_in[2];
    const float* g1 = (const float*)d_in[3];
    const float* b1 = (const float*)d_in[4];
    const float* g2 = (const float*)d_in[5];
    const float* b2 = (const float*)d_in[6];
    float* out = (float*)d_out;

    // ws: y2 compact (51.4MB) at 0; stats at +56MB.
    char* ws = (char*)d_ws;
    u16*   y2c  = (u16*)ws;
    float* st   = (float*)(ws + (size_t)(56u << 20));
    float* sums1 = st, *sums2 = st + 128;
    // d_out hosts y1 half-planes + repacked weights; dead before finalize writes.
    char*  oc   = (char*)d_out;
    u16*   y1p  = (u16*)oc;                            // 53.5 MB
    u16*   wt1  = (u16*)(oc + (size_t)(54u << 20));    // 2.25 MB
    u16*   wt2  = (u16*)(oc + (size_t)(58u << 20));    // 2.25 MB

    repack2_kernel<<<9217, 256, 0, stream>>>(w1, w2, wt1, wt2, st);

    conv_mfma<0><<<512, 448, 0, stream>>>(x, nullptr, wt1, y1p, sums1, st, g1, b1);
    conv_mfma<1><<<512, 448, 0, stream>>>(nullptr, y1p, wt2, y2c, sums2, sums1, g1, b1);
    finalize_kernel<<<dim3(112, 32), 256, 0, stream>>>(y2c, sums2, g2, b2, x, out);
}

// Round 22
// 177.101 us; speedup vs baseline: 1.1382x; 1.0176x over previous
//
#include <hip/hip_runtime.h>
#include <hip/hip_bf16.h>

// B=32, C=64, H=W=112. Per-sample 3x3 convs via bf16 MFMA implicit GEMM.
// conv1 stages B directly from x via PIXEL-SPACE dwordx4 gather; r23: task
// mapping is oct=task>>8, unit=task&255 so a wave's 64 lanes read 64
// CONSECUTIVE 16B chunks of ONE channel plane (1KB/instr coalescing), instead
// of 4 interleaved planes (256B/instr).
// conv2 reads y1 half-planes [b][half(ci32)][slot][32ci], slot = POFF+y*113+x.
// Conv block (448 thr = 7 waves): W staged via global_load_lds (73.7KB), one
// ci-half B window (64KB, 1024 slots, LINEAR 64B stride) in LDS; k-loop = pure
// {ds_read A, ds_read B, MFMA}. Wave = 64co x 112px (7 frags, acc[7][4]).
#define HW   112
#define HW2  12544
#define CH   64
#define NB   32
#define PRW  113
#define NP   12655          // interior slots per sample
#define POFF 128
#define PS   13056          // slots per half-plane per sample
#define NPC  (NB*HW2)
#define TPX  784            // pixels per conv tile (= 7 rows)

using u16 = unsigned short;
typedef __attribute__((ext_vector_type(8))) short bf16x8;   // 8 bf16 = 4 VGPRs
typedef __attribute__((ext_vector_type(4))) float f32x4;

__device__ __forceinline__ float b2f(u16 u) {
    union { unsigned int i; float f; } c;
    c.i = ((unsigned int)u) << 16;
    return c.f;
}
__device__ __forceinline__ u16 f2b(float f) {
    union { float f; unsigned int i; } c;
    c.f = f;
    unsigned int x = c.i;
    x += 0x7fffu + ((x >> 16) & 1u);   // RNE
    return (u16)(x >> 16);
}
// pair f32 -> packed bf16x2 (RNE) via v_cvt_pk_bf16_f32; a = low, b = high
__device__ __forceinline__ unsigned pk2(float a, float b) {
    __hip_bfloat162 h = __float22bfloat162_rn(float2{a, b});
    union { __hip_bfloat162 h; unsigned u; } c; c.h = h; return c.u;
}

// async global->LDS, 16B per lane; l must be the WAVE-UNIFORM base
// (HW dest = base + lane*16). Drained by __syncthreads' vmcnt(0).
__device__ __forceinline__ void gl2lds(const u16* g, u16* l) {
    __builtin_amdgcn_global_load_lds(
        (const __attribute__((address_space(1))) unsigned int*)g,
        (__attribute__((address_space(3))) unsigned int*)l, 16, 0, 0);
}

// MODE 0: conv1 (input = x f32 NCHW, transpose+pad+convert fused into staging;
//                output = y1 half-planes, interior slots only)
// MODE 1: conv2 (input = y1 half-planes with BN1 affine+ReLU applied during
//                staging, pad slots masked to 0; output = COMPACT y2 [b][pix][64])
// wt: bf16 [b][half][tap][kq][co][8ci] (73728 B / sample, matches LDS layout).
template<int MODE>
__global__ __launch_bounds__(448, 1)
void conv_mfma(const float* __restrict__ xf, const u16* __restrict__ img,
               const u16* __restrict__ wt,
               u16* __restrict__ outp, float* __restrict__ sums,
               const float* __restrict__ psums, const float* __restrict__ gamma,
               const float* __restrict__ beta)
{
    __shared__ u16 wl[36864];            // 73728 B weights, both halves
    __shared__ u16 bt[32768];            // 65536 B: 1024 slots x 32ci (one half)
    // XCD swizzle: 512 = 8 x 64 -> each XCD gets 4 whole samples.
    const int bid = (int)blockIdx.x;
    const int sid = (bid & 7) * 64 + (bid >> 3);
    const int b = sid >> 4, tile = sid & 15;
    const int p0 = tile * TPX;           // first pixel of tile
    const int w0 = tile * 791 - 114;     // staged window start (slot space)
    const int tid = threadIdx.x;
    const int lane = tid & 63, wave = tid >> 6;   // wave 0..6
    const int px = lane & 15, kg = lane >> 4;
    const u16* wtb = wt + (size_t)b * 36864;

    // ---- stage ALL weights: async gllds, waves 0-5, 12 chunks each ----
    if (tid < 384) {
#pragma unroll
        for (int i = 0; i < 12; ++i) {
            const int c = i * 384 + tid;                 // 4608 chunks exact
            gl2lds(wtb + (size_t)c * 8, wl + (size_t)(c - lane) * 8);
        }
    }

    // ---- BN1 params for MODE1 staging (q = tid&3 loop-invariant: 448%4==0) ----
    float sc0[8], bi0[8], sc1[8], bi1[8];
    if (MODE == 1) {
        const int q = tid & 3;
#pragma unroll
        for (int e = 0; e < 8; ++e) {
            int c0 = q * 8 + e, c1 = 32 + q * 8 + e;
            float m0 = psums[c0] * (1.f / NPC), m1 = psums[c1] * (1.f / NPC);
            float v0 = psums[64 + c0] * (1.f / NPC) - m0 * m0;
            float v1 = psums[64 + c1] * (1.f / NPC) - m1 * m1;
            sc0[e] = gamma[c0] * rsqrtf(v0 + 1e-5f); bi0[e] = beta[c0] - m0 * sc0[e];
            sc1[e] = gamma[c1] * rsqrtf(v1 + 1e-5f); bi1[e] = beta[c1] - m1 * sc1[e];
        }
    }
    const float* xb = (MODE == 0) ? xf + (size_t)b * CH * HW2 : nullptr;

    // pixel window start for MODE0 gather (4-aligned)
    int pl4 = 0;
    if (MODE == 0) {
        int pl = w0 - w0 / PRW;          // first pixel at/after slot w0
        if (pl < 0) pl = 0;
        pl4 = pl & ~3;
    }

    // MODE0 pixel-fill: oct = task>>8 (wave-uniform), unit = task&255 ->
    // consecutive lanes load consecutive 16B chunks of one plane (1KB/instr).
    auto pfill = [&](int task, int h) {
        const int oct = task >> 8, unit = task & 255;
        const int p_base = pl4 + unit * 4;
        const float* pp = xb + (size_t)(h * 32 + oct * 8) * HW2 + p_base;
        f32x4 q[8];
        if (p_base <= HW2 - 4) {
#pragma unroll
            for (int e = 0; e < 8; ++e) q[e] = *(const f32x4*)(pp + (size_t)e * HW2);
        } else {
#pragma unroll
            for (int e = 0; e < 8; ++e) {
                q[e] = (f32x4)0.f;
#pragma unroll
                for (int j = 0; j < 4; ++j)
                    if (p_base + j < HW2) q[e][j] = pp[(size_t)e * HW2 + j];
            }
        }
#pragma unroll
        for (int j = 0; j < 4; ++j) {
            const int p   = p_base + j;
            const int off = p + p / HW - w0;
            if ((unsigned)off < 1018u) {
                uint4 u;
                u.x = pk2(q[0][j], q[1][j]);
                u.y = pk2(q[2][j], q[3][j]);
                u.z = pk2(q[4][j], q[5][j]);
                u.w = pk2(q[6][j], q[7][j]);
                *(uint4*)(bt + off * 32 + oct * 8) = u;
            }
        }
    };

    // ---- stage B half 0 ----
    if (MODE == 0) {
        // zero-scan: lead/trail pads + border columns in the window (once; h=1
        // pixel-fill never touches these slots, so zeros persist).
#pragma unroll
        for (int i = 0; i < 3; ++i) {
            const int s = i * 448 + tid;
            if (s < 1018) {
                const int a = w0 + s;
                if (a < 0 || a >= NP || ((a + 226) % PRW) == PRW - 1) {
                    uint4 z = {0u, 0u, 0u, 0u};
#pragma unroll
                    for (int k = 0; k < 4; ++k) *(uint4*)(bt + s * 32 + k * 8) = z;
                }
            }
        }
#pragma unroll
        for (int i = 0; i < 2; ++i) pfill(i * 448 + tid, 0);
        if (tid < 128) pfill(896 + tid, 0);              // 1024 tasks total
    } else {
        const u16* bp = img + ((size_t)(b * 2 + 0) * PS + POFF + w0) * 32;
        auto st0 = [&](int c) {
            const int pt = w0 + (c >> 2);
            bf16x8 v = (bf16x8)0;
            bool val = ((unsigned)pt < (unsigned)NP) && (pt % PRW != PRW - 1);
            bf16x8 r = *(const bf16x8*)(bp + c * 8);
#pragma unroll
            for (int e = 0; e < 8; ++e) {
                float t = b2f((u16)r[e]) * sc0[e] + bi0[e];
                t = (val && t > 0.f) ? t : 0.f;
                v[e] = (short)f2b(t);
            }
            *(bf16x8*)(bt + c * 8) = v;
        };
#pragma unroll
        for (int i = 0; i < 9; ++i) st0(i * 448 + tid);
        if (tid < 64) st0(4032 + tid);
    }
    __syncthreads();

    // ---- per-fragment LDS slot bases (pixel -> slot, incl. row-border skips) ----
    int lsf[7];
#pragma unroll
    for (int f = 0; f < 7; ++f) {
        const int pix = p0 + (wave * 7 + f) * 16 + px;
        lsf[f] = pix + pix / HW - w0;    // in [114, 903]; +-114 stays in [0,1023]
    }

    f32x4 acc[7][4];
#pragma unroll
    for (int f = 0; f < 7; ++f)
#pragma unroll
        for (int m = 0; m < 4; ++m) acc[f][m] = (f32x4)0.f;

    // ---- main loop: 2 ci-halves x 9 taps; pure LDS + MFMA ----
#pragma unroll
    for (int h = 0; h < 2; ++h) {
        if (h == 1) {
            __syncthreads();             // all waves done with half-0 B tile
            if (MODE == 0) {
#pragma unroll
                for (int i = 0; i < 2; ++i) pfill(i * 448 + tid, 1);
                if (tid < 128) pfill(896 + tid, 1);
            } else {
                const u16* bp = img + ((size_t)(b * 2 + 1) * PS + POFF + w0) * 32;
                auto st1 = [&](int c) {
                    const int pt = w0 + (c >> 2);
                    bf16x8 v = (bf16x8)0;
                    bool val = ((unsigned)pt < (unsigned)NP) && (pt % PRW != PRW - 1);
                    bf16x8 r = *(const bf16x8*)(bp + c * 8);
#pragma unroll
                    for (int e = 0; e < 8; ++e) {
                        float t = b2f((u16)r[e]) * sc1[e] + bi1[e];
                        t = (val && t > 0.f) ? t : 0.f;
                        v[e] = (short)f2b(t);
                    }
                    *(bf16x8*)(bt + c * 8) = v;
                };
#pragma unroll
                for (int i = 0; i < 9; ++i) st1(i * 448 + tid);
                if (tid < 64) st1(4032 + tid);
            }
            __syncthreads();
        }
#pragma unroll
        for (int tap = 0; tap < 9; ++tap) {
            const int off = (tap / 3 - 1) * PRW + (tap % 3 - 1);
            bf16x8 Af[4];
#pragma unroll
            for (int m = 0; m < 4; ++m)
                Af[m] = *(const bf16x8*)(wl + h * 18432 + tap * 2048 + kg * 512 + (m * 16 + px) * 8);
#pragma unroll
            for (int f = 0; f < 7; ++f) {
                bf16x8 Bf = *(const bf16x8*)(bt + (lsf[f] + off) * 32 + kg * 8);
#pragma unroll
                for (int m = 0; m < 4; ++m)
                    acc[f][m] = __builtin_amdgcn_mfma_f32_16x16x32_bf16(Af[m], Bf, acc[f][m], 0, 0, 0);
            }
        }
    }

    // ---- epilogue: unpredicated stores + fused BN batch-stat partials ----
    float s_[4][4], sq[4][4];
#pragma unroll
    for (int m = 0; m < 4; ++m)
#pragma unroll
        for (int q = 0; q < 4; ++q) { s_[m][q] = 0.f; sq[m][q] = 0.f; }

#pragma unroll
    for (int f = 0; f < 7; ++f) {
        const int pix  = p0 + (wave * 7 + f) * 16 + px;
        const int slot = pix + pix / HW;
#pragma unroll
        for (int m = 0; m < 4; ++m) {
            float v0 = acc[f][m][0], v1 = acc[f][m][1], v2 = acc[f][m][2], v3 = acc[f][m][3];
            s_[m][0] += v0; s_[m][1] += v1; s_[m][2] += v2; s_[m][3] += v3;
            sq[m][0] += v0 * v0; sq[m][1] += v1 * v1;
            sq[m][2] += v2 * v2; sq[m][3] += v3 * v3;
            uint2 pk;
            pk.x = ((unsigned)f2b(v1) << 16) | f2b(v0);
            pk.y = ((unsigned)f2b(v3) << 16) | f2b(v2);
            if (MODE == 0) {
                // y1 half-planes: half = m>>1, within-half co = (m&1)*16+kg*4
                u16* dst = outp + ((size_t)(b * 2 + (m >> 1)) * PS + POFF + slot) * 32
                                + (m & 1) * 16 + kg * 4;
                *(uint2*)dst = pk;
            } else {
                // compact y2 [b][pix][64]
                u16* dst = outp + ((size_t)b * HW2 + pix) * 64 + m * 16 + kg * 4;
                *(uint2*)dst = pk;
            }
        }
    }
#pragma unroll
    for (int off = 1; off < 16; off <<= 1) {
#pragma unroll
        for (int m = 0; m < 4; ++m)
#pragma unroll
            for (int q = 0; q < 4; ++q) {
                s_[m][q] += __shfl_xor(s_[m][q], off);
                sq[m][q] += __shfl_xor(sq[m][q], off);
            }
    }
    __syncthreads();                     // bt reads done; reuse as reduce buffer
    float* red = (float*)bt;             // 7 waves x 128 floats
    if (px == 0) {
#pragma unroll
        for (int m = 0; m < 4; ++m)
#pragma unroll
            for (int q = 0; q < 4; ++q) {
                int c = m * 16 + kg * 4 + q;
                red[wave * 128 + c]      = s_[m][q];
                red[wave * 128 + 64 + c] = sq[m][q];
            }
    }
    __syncthreads();
    if (tid < 128) {
        float t = 0.f;
#pragma unroll
        for (int k = 0; k < 7; ++k) t += red[k * 128 + tid];
        atomicAdd(&sums[tid], t);
    }
}

// both weights: [b][co][ci][3][3] f32 -> [b][half][tap][kq][co][8ci] bf16.
// Extra trailing block zeroes the stats area.
__global__ __launch_bounds__(256)
void repack2_kernel(const float* __restrict__ w1, const float* __restrict__ w2,
                    u16* __restrict__ wt1, u16* __restrict__ wt2,
                    float* __restrict__ st)
{
    if (blockIdx.x == 9216) {
        st[threadIdx.x] = 0.f;           // 256 floats (sums1 + sums2)
        return;
    }
    int i = blockIdx.x * 256 + threadIdx.x;      // 0..2359295
    const int N = NB * 36864;
    const float* w = (i < N) ? w1 : w2;
    u16* wt = (i < N) ? wt1 : wt2;
    int o = (i < N) ? i : i - N;
    int b = o / 36864, r = o - b * 36864;
    int half = r / 18432; r -= half * 18432;
    int tap  = r / 2048;  r -= tap * 2048;
    int kq   = r / 512;   r -= kq * 512;
    int co   = r / 8;
    int ci   = half * 32 + kq * 8 + (r & 7);
    wt[o] = f2b(w[(((size_t)b * 64 + co) * 64 + ci) * 9 + tap]);
}

// out = relu(bn2(y2) + x), NCHW f32 via LDS transpose; y2 compact [b][pix][64]
__global__ __launch_bounds__(256)
void finalize_kernel(const u16* __restrict__ y2, const float* __restrict__ sums,
                     const float* __restrict__ gamma, const float* __restrict__ beta,
                     const float* __restrict__ x, float* __restrict__ out)
{
    __shared__ float lt[64][116];
    __shared__ float sbl[128];
    const int b = blockIdx.y, y = blockIdx.x;
    const int tid = threadIdx.x;
    if (tid < 64) {
        float mean = sums[tid] * (1.f / NPC);
        float var  = sums[64 + tid] * (1.f / NPC) - mean * mean;
        float sc   = gamma[tid] * rsqrtf(var + 1e-5f);
        sbl[tid]      = sc;
        sbl[64 + tid] = beta[tid] - mean * sc;
    }
    __syncthreads();
    const u16* rowp = y2 + ((size_t)b * HW2 + (size_t)y * HW) * 64;
    {
        const int cg = tid & 7;
        float sc[8], bi[8];
#pragma unroll
        for (int e = 0; e < 8; ++e) { sc[e] = sbl[cg * 8 + e]; bi[e] = sbl[64 + cg * 8 + e]; }
        for (int t = tid; t < HW * 8; t += 256) {
            int px = t >> 3;
            bf16x8 v = *(const bf16x8*)(rowp + px * 64 + cg * 8);
#pragma unroll
            for (int e = 0; e < 8; ++e)
                lt[cg * 8 + e][px] = b2f((u16)v[e]) * sc[e] + bi[e];
        }
    }
    __syncthreads();
    {
        const int c = tid >> 2, xg = (tid & 3) * 28;
        size_t base = ((size_t)b * CH + c) * HW2 + (size_t)y * HW + xg;
#pragma unroll
        for (int i = 0; i < 7; ++i) {
            float4 xv = *(const float4*)(x + base + i * 4);
            float4 r;
            r.x = fmaxf(lt[c][xg + i * 4 + 0] + xv.x, 0.f);
            r.y = fmaxf(lt[c][xg + i * 4 + 1] + xv.y, 0.f);
            r.z = fmaxf(lt[c][xg + i * 4 + 2] + xv.z, 0.f);
            r.w = fmaxf(lt[c][xg + i * 4 + 3] + xv.w, 0.f);
            *(float4*)(out + base + i * 4) = r;
        }
    }
}

extern "C" void kernel_launch(void* const* d_in, const int* in_sizes, int n_in,
                              void* d_out, int out_size, void* d_ws, size_t ws_size,
                              hipStream_t stream)
{
    const float* x  = (const float*)d_in[0];
    const float* w1 = (const float*)d_in[1];
    const float* w2 = (const float*)d_in[2];
    const float* g1 = (const float*)d_in[3];
    const float* b1 = (const float*)d_in[4];
    const float* g2 = (const float*)d_in[5];
    const float* b2 = (const float*)d_in[6];
    float* out = (float*)d_out;

    // ws: y2 compact (51.4MB) at 0; stats at +56MB.
    char* ws = (char*)d_ws;
    u16*   y2c  = (u16*)ws;
    float* st   = (float*)(ws + (size_t)(56u << 20));
    float* sums1 = st, *sums2 = st + 128;
    // d_out hosts y1 half-planes + repacked weights; dead before finalize writes.
    char*  oc   = (char*)d_out;
    u16*   y1p  = (u16*)oc;                            // 53.5 MB
    u16*   wt1  = (u16*)(oc + (size_t)(54u << 20));    // 2.25 MB
    u16*   wt2  = (u16*)(oc + (size_t)(58u << 20));    // 2.25 MB

    repack2_kernel<<<9217, 256, 0, stream>>>(w1, w2, wt1, wt2, st);

    conv_mfma<0><<<512, 448, 0, stream>>>(x, nullptr, wt1, y1p, sums1, st, g1, b1);
    conv_mfma<1><<<512, 448, 0, stream>>>(nullptr, y1p, wt2, y2c, sums2, sums1, g1, b1);
    finalize_kernel<<<dim3(112, 32), 256, 0, stream>>>(y2c, sums2, g2, b2, x, out);
}